// Round 8
// baseline (177.064 us; speedup 1.0000x reference)
//
#include <hip/hip_runtime.h>
#include <math.h>

typedef unsigned int u32;

#define N_TOTAL 500000
#define P_NODES 21
#define KNEG    5
#define DDIM    128
#define BATCH   1024
#define N_PAIRS 185
#define N_NEG   (N_PAIRS * KNEG)     // 925
#define NEG_PB  463                  // ceil(925/2) neg tasks per block
#define POS_PB  93                   // ceil(185/2) pos tasks per block

#define TBL_BYTES ((size_t)N_TOTAL * 128)        // 64 MB fp8 table
#define CONV_BLOCKS ((N_TOTAL * DDIM / 16) / 256)  // 15625

struct Pairs { unsigned char pi[N_PAIRS]; unsigned char pj[N_PAIRS]; };

constexpr Pairs make_pairs() {
    Pairs p{};
    int n = 0;
    for (int i = 0; i < P_NODES; ++i) {
        int jlo = (i - KNEG > 0) ? i - KNEG : 0;
        int jhi = (i + KNEG < P_NODES) ? i + KNEG : P_NODES;
        for (int j = jlo; j < jhi; ++j) { p.pi[n] = (unsigned char)i; p.pj[n] = (unsigned char)j; ++n; }
    }
    return p;
}

__constant__ Pairs PAIRS = make_pairs();

__device__ __forceinline__ float lsig(float x) {
    return -__logf(1.f + __expf(-x));   // dots are tiny; no overflow risk
}

__device__ __forceinline__ float dot4(float4 a, float4 b) {
    return fmaf(a.x, b.x, fmaf(a.y, b.y, fmaf(a.z, b.z, a.w * b.w)));
}

__device__ __forceinline__ int divk(int q) {        // q/5 exact for q < 2^18
    return (int)(((u32)q * 52429u) >> 18);
}

// ---- custom e4m3 (bias 7) codec, pure bit ops: no builtins, no host/device divergence ----
__device__ __forceinline__ u32 enc1(float x) {
    u32 u = __float_as_uint(x * 0x1p-120f);          // target bits now at [26:20]
    u32 s = (u >> 24) & 0x80u;
    u &= 0x7fffffffu;
    u += 0x7FFFFu + ((u >> 20) & 1u);                // RNE at bit 20
    return s | ((u >> 20) & 0x7fu);
}
__device__ __forceinline__ float dec1(u32 b) {
    u32 bits = ((b << 20) & 0x07f00000u) | ((b << 24) & 0x80000000u);
    return __uint_as_float(bits) * 0x1p+120f;
}
// decode 4 packed fp8 from a dword, dot against a float4
__device__ __forceinline__ float dot_pk(u32 d, float4 c) {
    float r;
    r  = dec1( d         & 0xffu) * c.x;
    r += dec1((d >>  8u) & 0xffu) * c.y;
    r += dec1((d >> 16u) & 0xffu) * c.z;
    r += dec1( d >> 24u         ) * c.w;
    return r;
}

// ---------------- k_conv: stream f32 table -> fp8 table (1 line per row) ----------------
__global__ __launch_bounds__(256) void k_conv(const float4* __restrict__ src,
                                              uint4* __restrict__ dst) {
    int t = blockIdx.x * 256 + threadIdx.x;          // 4,000,000 threads, 16 elems each
    float4 a = src[4 * (size_t)t + 0];
    float4 b = src[4 * (size_t)t + 1];
    float4 c = src[4 * (size_t)t + 2];
    float4 d = src[4 * (size_t)t + 3];
    u32 w0 = enc1(a.x) | (enc1(a.y) << 8) | (enc1(a.z) << 16) | (enc1(a.w) << 24);
    u32 w1 = enc1(b.x) | (enc1(b.y) << 8) | (enc1(b.z) << 16) | (enc1(b.w) << 24);
    u32 w2 = enc1(c.x) | (enc1(c.y) << 8) | (enc1(c.z) << 16) | (enc1(c.w) << 24);
    u32 w3 = enc1(d.x) | (enc1(d.y) << 8) | (enc1(d.z) << 16) | (enc1(d.w) << 24);
    dst[t] = make_uint4(w0, w1, w2, w3);
}

// ---------------- k_main: 2 blocks per b; pos from LDS f32, neg rows = 1 line fp8 ----------------
__global__ __launch_bounds__(256) void k_main(
    const float* __restrict__ emb,
    const int*   __restrict__ path,
    const int*   __restrict__ neg,
    const uint4* __restrict__ tbl4,
    float*       __restrict__ out)
{
    __shared__ float4 crow[P_NODES * 32];     // 10.5 KB, slot rotated by row
    __shared__ int    nidx[NEG_PB];
    __shared__ int    pidx[P_NODES];
    __shared__ unsigned char spi[N_PAIRS];
    __shared__ unsigned char spj[N_PAIRS];

    const int blk = blockIdx.x;
    const int b   = blk >> 1;
    const int h   = blk & 1;
    const int t   = threadIdx.x;
    const int n0  = h * NEG_PB;
    const int n1  = min(N_NEG, n0 + NEG_PB);
    const int p0  = h * POS_PB;
    const int p1  = min(N_PAIRS, p0 + POS_PB);

    if (t < P_NODES) pidx[t] = path[b * P_NODES + t];
    if (t < N_PAIRS) { spi[t] = PAIRS.pi[t]; spj[t] = PAIRS.pj[t]; }
    for (int q = n0 + t; q < n1; q += 256) {
        int p = divk(q);
        int k = q - p * KNEG;
        nidx[q - n0] = neg[(size_t)p * (BATCH * KNEG) + b * KNEG + k];
    }
    __syncthreads();   // pidx ready
    for (int e = t; e < P_NODES * 32; e += 256) {
        int r = e >> 5, c = e & 31;
        float4 val = ((const float4*)(emb + (size_t)pidx[r] * DDIM))[c];
        crow[r * 32 + ((c + r) & 31)] = val;
    }
    __syncthreads();   // crow + nidx ready; no more barriers

    const int g = t >> 3;          // 8-lane group 0..31
    const int m = t & 7;           // phase within group

    float acc = 0.f;

    // ---- pos tasks: both rows from LDS (exact f32); lane m covers float4-cols m,m+8,m+16,m+24 ----
    for (int s = p0 + g; s < p1; s += 32) {
        int ci = spi[s], cj = spj[s];
        float part = 0.f;
        #pragma unroll
        for (int i = 0; i < 4; ++i) {
            int c = m + 8 * i;
            part += dot4(crow[cj * 32 + ((c + cj) & 31)], crow[ci * 32 + ((c + ci) & 31)]);
        }
        part += __shfl_xor(part, 1);
        part += __shfl_xor(part, 2);
        part += __shfl_xor(part, 4);
        acc += lsig(part);                   // counted 8x (m duplicates)
    }

    // ---- neg tasks: one uint4 load per lane; 8-lane group covers the full 128B row ----
    for (int base = n0; base < n1; base += 128) {
        uint4 rv[4];
        int   civ[4];
        bool  vv[4];

        #pragma unroll
        for (int k = 0; k < 4; ++k) {
            int qq = base + g * 4 + k;
            bool v = qq < n1;
            vv[k] = v;
            int qc = v ? qq : n0;
            civ[k] = spi[divk(qc)];
            rv[k] = tbl4[(size_t)nidx[qc - n0] * 8 + m];
        }

        #pragma unroll
        for (int k = 0; k < 4; ++k) {
            int ci = civ[k];
            float part;
            part  = dot_pk(rv[k].x, crow[ci * 32 + ((4 * m + 0 + ci) & 31)]);
            part += dot_pk(rv[k].y, crow[ci * 32 + ((4 * m + 1 + ci) & 31)]);
            part += dot_pk(rv[k].z, crow[ci * 32 + ((4 * m + 2 + ci) & 31)]);
            part += dot_pk(rv[k].w, crow[ci * 32 + ((4 * m + 3 + ci) & 31)]);
            part += __shfl_xor(part, 1);
            part += __shfl_xor(part, 2);
            part += __shfl_xor(part, 4);
            if (vv[k]) acc += lsig(-part);   // counted 8x
        }
    }

    // ---- wave reduce; 8x duplication scaled out ----
    acc += __shfl_xor(acc, 32);
    acc += __shfl_xor(acc, 16);
    acc += __shfl_xor(acc, 8);
    acc += __shfl_xor(acc, 4);
    acc += __shfl_xor(acc, 2);
    acc += __shfl_xor(acc, 1);
    if ((t & 63) == 0)
        atomicAdd(out, acc * (-1.f / (8.f * (float)BATCH)));
}

// ================= fallback (R6 kernel, verbatim) if ws is too small =================
#define NTASK_F (N_PAIRS + N_NEG)
#define HALF_T  (NTASK_F / 2)

__global__ __launch_bounds__(256) void mp2v_fallback(
    const float* __restrict__ emb, const int* __restrict__ path,
    const int* __restrict__ neg, float* __restrict__ out)
{
    __shared__ float4 crow[P_NODES * 32];
    __shared__ int    nidxf[N_NEG];
    __shared__ int    pidx[P_NODES];
    __shared__ unsigned char spi[N_PAIRS];
    __shared__ unsigned char spj[N_PAIRS];

    const int blk = blockIdx.x;
    const int b   = blk >> 1;
    const int q0  = (blk & 1) * HALF_T;
    const int q1  = q0 + HALF_T;
    const int t   = threadIdx.x;

    if (t < P_NODES) pidx[t] = path[b * P_NODES + t];
    if (t < N_PAIRS) { spi[t] = PAIRS.pi[t]; spj[t] = PAIRS.pj[t]; }
    for (int q = t; q < N_NEG; q += 256) {
        int p = divk(q);
        int k = q - p * KNEG;
        nidxf[q] = neg[(size_t)p * (BATCH * KNEG) + b * KNEG + k];
    }
    __syncthreads();
    for (int e = t; e < P_NODES * 32; e += 256) {
        int r = e >> 5, c = e & 31;
        float4 val = ((const float4*)(emb + (size_t)pidx[r] * DDIM))[c];
        crow[r * 32 + ((c + r) & 31)] = val;
    }
    __syncthreads();

    const int g = t >> 3, m = t & 7;
    const float4* emb4 = (const float4*)emb;
    float acc = 0.f;

    for (int base = q0; base < q1; base += 128) {
        float4 rv[4][4];
        int civ[4]; float sg[4]; bool vv[4];
        #pragma unroll
        for (int k = 0; k < 4; ++k) {
            int qq = base + g * 4 + k;
            bool v = qq < q1; vv[k] = v;
            int qc = v ? qq : q0;
            if (qc < N_NEG) {
                int p = divk(qc);
                civ[k] = spi[p]; sg[k] = -1.f;
                const float4* R = emb4 + (size_t)nidxf[qc] * 32;
                #pragma unroll
                for (int i = 0; i < 4; ++i) rv[k][i] = R[m + 8 * i];
            } else {
                int pp = qc - N_NEG;
                int cj = spj[pp];
                civ[k] = spi[pp]; sg[k] = 1.f;
                #pragma unroll
                for (int i = 0; i < 4; ++i) {
                    int c = m + 8 * i;
                    rv[k][i] = crow[cj * 32 + ((c + cj) & 31)];
                }
            }
        }
        #pragma unroll
        for (int k = 0; k < 4; ++k) {
            int ci = civ[k];
            float part = 0.f;
            #pragma unroll
            for (int i = 0; i < 4; ++i) {
                int c = m + 8 * i;
                part += dot4(rv[k][i], crow[ci * 32 + ((c + ci) & 31)]);
            }
            part += __shfl_xor(part, 1);
            part += __shfl_xor(part, 2);
            part += __shfl_xor(part, 4);
            if (vv[k]) acc += lsig(sg[k] * part);
        }
    }
    acc += __shfl_xor(acc, 32);
    acc += __shfl_xor(acc, 16);
    acc += __shfl_xor(acc, 8);
    acc += __shfl_xor(acc, 4);
    acc += __shfl_xor(acc, 2);
    acc += __shfl_xor(acc, 1);
    if ((t & 63) == 0) atomicAdd(out, acc * (-1.f / (8.f * (float)BATCH)));
}

extern "C" void kernel_launch(void* const* d_in, const int* in_sizes, int n_in,
                              void* d_out, int out_size, void* d_ws, size_t ws_size,
                              hipStream_t stream) {
    const float* emb  = (const float*)d_in[0];
    const int*   path = (const int*)d_in[1];
    const int*   neg  = (const int*)d_in[2];
    float*       out  = (float*)d_out;

    hipMemsetAsync(out, 0, sizeof(float), stream);

    if (ws_size >= TBL_BYTES) {
        k_conv<<<CONV_BLOCKS, 256, 0, stream>>>((const float4*)emb, (uint4*)d_ws);
        k_main<<<BATCH * 2, 256, 0, stream>>>(emb, path, neg, (const uint4*)d_ws, out);
    } else {
        mp2v_fallback<<<BATCH * 2, 256, 0, stream>>>(emb, path, neg, out);
    }
}